// Round 1
// baseline (22299.811 us; speedup 1.0000x reference)
//
#include <hip/hip_runtime.h>
#include <cstdint>
#include <cstddef>

// Problem constants: B=64, D=512, T=1024, L=512
// Pipeline:
//   K1: z = LayerNorm(cos(x^T @ rff_w + rff_b))          [65536 x 512]
//   K2: gates = act([z_t || z_{t-1}] @ [W|R] + bias)      [rows x 1536] (i,f sigmoid; g tanh)
//   K3: c_t = f*c + i*g ; h = sin(z)*c ; out[b][l][t]     (LDS tile transpose)

// ---------------------------------------------------------------- Kernel 1
// GEMM M=65536 K=512 N=512, BM=64, BN=512 (full row -> fuse LayerNorm), BK=16
// 256 threads (tx 0..15, ty 0..15); each thread: 4 rows x 32 cols (8 float4 slices).
__global__ __launch_bounds__(256, 2) void k1_gemm_ln(
    const float* __restrict__ x, const float* __restrict__ W,
    const float* __restrict__ bias, float* __restrict__ z)
{
  __shared__ float As[16][64];    // [k][m]
  __shared__ float Bs[16][512];   // [k][n]  32 KB
  const int tid = threadIdx.x;
  const int tx = tid & 15, ty = tid >> 4;
  const int rb = blockIdx.x * 64;     // global row base (rows = b*1024 + t)
  const int b  = rb >> 10;
  const int t0 = rb & 1023;           // 64 | 1024 -> one b per block

  float acc[4][32];
#pragma unroll
  for (int i = 0; i < 4; ++i)
#pragma unroll
    for (int j = 0; j < 32; ++j) acc[i][j] = 0.f;

  const float* xb = x + ((size_t)b * 512) * 1024 + t0;  // x[b][k][t0+..]

  for (int k0 = 0; k0 < 512; k0 += 16) {
    // A tile: 16 k-rows x 64 m; x is [B][D][T], t contiguous == m contiguous.
    {
      const int k = tid >> 4, m4 = (tid & 15) * 4;
      const float4 v = *(const float4*)(xb + (size_t)(k0 + k) * 1024 + m4);
      *(float4*)&As[k][m4] = v;
    }
    // B tile: 16 x 512 from rff_w (row-major [D][L])
    {
      const int n4 = (tid & 127) * 4;
      const int kb = tid >> 7;  // 0..1
#pragma unroll
      for (int p = 0; p < 8; ++p) {
        const int k = kb + p * 2;
        *(float4*)&Bs[k][n4] = *(const float4*)(W + (size_t)(k0 + k) * 512 + n4);
      }
    }
    __syncthreads();
#pragma unroll
    for (int k = 0; k < 16; ++k) {
      float a[4];
      { float4 t4 = *(float4*)&As[k][ty * 4]; a[0]=t4.x; a[1]=t4.y; a[2]=t4.z; a[3]=t4.w; }
#pragma unroll
      for (int q = 0; q < 8; ++q) {
        const float4 b4 = *(float4*)&Bs[k][tx * 4 + q * 64];
#pragma unroll
        for (int i = 0; i < 4; ++i) {
          acc[i][q*4+0] = fmaf(a[i], b4.x, acc[i][q*4+0]);
          acc[i][q*4+1] = fmaf(a[i], b4.y, acc[i][q*4+1]);
          acc[i][q*4+2] = fmaf(a[i], b4.z, acc[i][q*4+2]);
          acc[i][q*4+3] = fmaf(a[i], b4.w, acc[i][q*4+3]);
        }
      }
    }
    __syncthreads();
  }

  // Epilogue: v = cos(acc + bias); LayerNorm over the 512-wide row; write z.
#pragma unroll
  for (int i = 0; i < 4; ++i) {
    float s = 0.f, s2 = 0.f;
#pragma unroll
    for (int q = 0; q < 8; ++q)
#pragma unroll
      for (int j = 0; j < 4; ++j) {
        const int col = tx * 4 + q * 64 + j;
        const float v = cosf(acc[i][q*4+j] + bias[col]);
        acc[i][q*4+j] = v;
        s += v; s2 += v * v;
      }
    // reduce across the 16 tx lanes sharing this row (same wave: lane = ty*16+tx)
#pragma unroll
    for (int m = 1; m < 16; m <<= 1) {
      s  += __shfl_xor(s,  m, 16);
      s2 += __shfl_xor(s2, m, 16);
    }
    const float mean = s * (1.f / 512.f);
    const float var  = s2 * (1.f / 512.f) - mean * mean;
    const float inv  = rsqrtf(var + 1e-5f);
    const size_t row = (size_t)(rb + ty * 4 + i) * 512;
#pragma unroll
    for (int q = 0; q < 8; ++q) {
      float ov[4];
#pragma unroll
      for (int j = 0; j < 4; ++j) ov[j] = (acc[i][q*4+j] - mean) * inv;
      *(float4*)(z + row + tx * 4 + q * 64) = *(float4*)ov;
    }
  }
}

// ---------------------------------------------------------------- Kernel 2
// Gate GEMM: A2 = [z_t || z_{t-1}] (K=1024), W2 = [W|R] per gate, N=1536.
// BM=64, BN=256, BK=16; 256 threads; thread: 4 rows x 16 cols.
__global__ __launch_bounds__(256, 2) void k2_gates(
    const float* __restrict__ z, const float* __restrict__ initl,
    const float* __restrict__ w0, const float* __restrict__ w1, const float* __restrict__ w2,
    const float* __restrict__ r0, const float* __restrict__ r1, const float* __restrict__ r2,
    const float* __restrict__ b0, const float* __restrict__ b1, const float* __restrict__ b2,
    float* __restrict__ gates, int tc, int Tc)
{
  __shared__ float As[16][64];
  __shared__ float Bs[16][256];
  const int tid = threadIdx.x;
  const int tx = tid & 15, ty = tid >> 4;
  const int nb_per_b = Tc >> 6;
  const int bm = blockIdx.x;
  const int b  = bm / nb_per_b;
  const int t0 = tc + (bm % nb_per_b) * 64;
  const int n0 = blockIdx.y * 256;     // 0..1280
  const int sel = n0 >> 9;             // 0:i 1:f 2:g
  const int nl0 = n0 & 511;            // 0 or 256
  const float* Wk = sel == 0 ? w0 : (sel == 1 ? w1 : w2);
  const float* Rk = sel == 0 ? r0 : (sel == 1 ? r1 : r2);
  const float* bb = sel == 0 ? b0 : (sel == 1 ? b1 : b2);

  float acc[4][16];
#pragma unroll
  for (int i = 0; i < 4; ++i)
#pragma unroll
    for (int j = 0; j < 16; ++j) acc[i][j] = 0.f;

  const int am  = tid >> 2;         // 0..63 (row within tile)
  const int ak  = (tid & 3) * 4;    // k offset within tile
  const int t_a = t0 + am;
  const int rg  = b * 1024 + t_a;   // global z row

  for (int k0 = 0; k0 < 1024; k0 += 16) {
    // A tile: [z_t] for k<512, [z_{t-1} | init_latent] for k>=512
    float4 av;
    if (k0 < 512) {
      av = *(const float4*)(z + (size_t)rg * 512 + k0 + ak);
    } else if (t_a == 0) {
      av = *(const float4*)(initl + (k0 - 512) + ak);
    } else {
      av = *(const float4*)(z + (size_t)(rg - 1) * 512 + (k0 - 512) + ak);
    }
    As[ak + 0][am] = av.x; As[ak + 1][am] = av.y;
    As[ak + 2][am] = av.z; As[ak + 3][am] = av.w;

    // B tile: 16 x 256 from W or R (row-major [L][L], slice cols nl0..nl0+255)
    const float* src = (k0 < 512) ? (Wk + (size_t)k0 * 512 + nl0)
                                  : (Rk + (size_t)(k0 - 512) * 512 + nl0);
    {
      const int n4 = (tid & 63) * 4;
      const int kb = tid >> 6;  // 0..3
#pragma unroll
      for (int p = 0; p < 4; ++p) {
        const int k = kb + p * 4;
        *(float4*)&Bs[k][n4] = *(const float4*)(src + (size_t)k * 512 + n4);
      }
    }
    __syncthreads();
#pragma unroll
    for (int k = 0; k < 16; ++k) {
      float a[4];
      { float4 t4 = *(float4*)&As[k][ty * 4]; a[0]=t4.x; a[1]=t4.y; a[2]=t4.z; a[3]=t4.w; }
#pragma unroll
      for (int q = 0; q < 4; ++q) {
        const float4 b4 = *(float4*)&Bs[k][tx * 4 + q * 64];
#pragma unroll
        for (int i = 0; i < 4; ++i) {
          acc[i][q*4+0] = fmaf(a[i], b4.x, acc[i][q*4+0]);
          acc[i][q*4+1] = fmaf(a[i], b4.y, acc[i][q*4+1]);
          acc[i][q*4+2] = fmaf(a[i], b4.z, acc[i][q*4+2]);
          acc[i][q*4+3] = fmaf(a[i], b4.w, acc[i][q*4+3]);
        }
      }
    }
    __syncthreads();
  }

  // Epilogue: bias + activation, write chunk-local gates[rl][1536]
  const size_t rl0 = (size_t)b * Tc + (t0 - tc);
#pragma unroll
  for (int i = 0; i < 4; ++i) {
    const size_t rowoff = (rl0 + ty * 4 + i) * 1536;
#pragma unroll
    for (int q = 0; q < 4; ++q) {
      float ov[4];
#pragma unroll
      for (int j = 0; j < 4; ++j) {
        const int nl = nl0 + tx * 4 + q * 64 + j;
        const float u = acc[i][q*4+j] + bb[nl];
        ov[j] = (sel < 2) ? (1.f / (1.f + __expf(-u))) : tanhf(u);
      }
      *(float4*)(gates + rowoff + n0 + tx * 4 + q * 64) = *(float4*)ov;
    }
  }
}

// ---------------------------------------------------------------- Kernel 3
// Sequential scan over t; LDS 128x33 tile for coalesced [B,L,T] stores.
__global__ __launch_bounds__(128, 4) void k3_scan(
    const float* __restrict__ gates, const float* __restrict__ z,
    const float* __restrict__ initc, float* __restrict__ out,
    float* __restrict__ cbuf, int tc, int Tc)
{
  __shared__ float tile[128][33];
  const int tid = threadIdx.x;
  const int b = blockIdx.y;
  const int l = blockIdx.x * 128 + tid;
  float c = (tc == 0) ? initc[l] : cbuf[b * 512 + l];
  const float* gb = gates + (size_t)b * Tc * 1536;
  const float* zb = z + ((size_t)b * 1024 + tc) * 512;

  for (int tt = 0; tt < Tc; tt += 32) {
#pragma unroll 4
    for (int j = 0; j < 32; ++j) {
      const int tau = tt + j;
      const float iv = gb[(size_t)tau * 1536 + l];
      const float fv = gb[(size_t)tau * 1536 + 512 + l];
      const float gv = gb[(size_t)tau * 1536 + 1024 + l];
      const float zv = zb[(size_t)tau * 512 + l];
      c = fmaf(fv, c, iv * gv);
      tile[tid][j] = sinf(zv) * c;
    }
    __syncthreads();
    const int col = tid & 31;
    const int rbase = tid >> 5;   // 0..3
    const size_t obase =
        ((size_t)b * 512 + blockIdx.x * 128) * 1024 + (size_t)(tc + tt) + col;
#pragma unroll
    for (int p = 0; p < 32; ++p) {
      const int row = rbase + p * 4;
      out[obase + (size_t)row * 1024] = tile[row][col];
    }
    __syncthreads();
  }
  cbuf[b * 512 + l] = c;
}

// ---------------------------------------------------------------- launcher
extern "C" void kernel_launch(void* const* d_in, const int* in_sizes, int n_in,
                              void* d_out, int out_size, void* d_ws, size_t ws_size,
                              hipStream_t stream)
{
  const float* x  = (const float*)d_in[0];
  const float* W  = (const float*)d_in[1];
  const float* rb = (const float*)d_in[2];
  const float* wi = (const float*)d_in[3];
  const float* wf = (const float*)d_in[4];
  const float* wc = (const float*)d_in[5];
  const float* ri = (const float*)d_in[6];
  const float* rf = (const float*)d_in[7];
  const float* rc = (const float*)d_in[8];
  const float* bi = (const float*)d_in[9];
  const float* bf = (const float*)d_in[10];
  const float* bc = (const float*)d_in[11];
  const float* il = (const float*)d_in[12];
  const float* ic = (const float*)d_in[13];
  float* out = (float*)d_out;

  char* ws = (char*)d_ws;
  const size_t zbytes = (size_t)65536 * 512 * 4;   // 134 MB
  float* z     = (float*)ws;
  float* cbuf  = (float*)(ws + zbytes);            // 128 KB (pad to 256 KB)
  float* gates = (float*)(ws + zbytes + 262144);

  // Adaptive time-chunk so z + gate chunk fit in ws.
  int Tc = 1024;
  while (Tc > 64) {
    const size_t need = zbytes + 262144 + (size_t)64 * Tc * 1536 * 4;
    if (need <= ws_size) break;
    Tc >>= 1;
  }

  k1_gemm_ln<<<dim3(1024), dim3(256), 0, stream>>>(x, W, rb, z);
  for (int tc = 0; tc < 1024; tc += Tc) {
    k2_gates<<<dim3(Tc, 6), dim3(256), 0, stream>>>(
        z, il, wi, wf, wc, ri, rf, rc, bi, bf, bc, gates, tc, Tc);
    k3_scan<<<dim3(4, 64), dim3(128), 0, stream>>>(gates, z, ic, out, cbuf, tc, Tc);
  }
}

// Round 2
// 1354.221 us; speedup vs baseline: 16.4669x; 16.4669x over previous
//
#include <hip/hip_runtime.h>
#include <hip/hip_bf16.h>
#include <cstdint>
#include <cstddef>

// B=64, D=512, T=1024, L=512
// prep:  xt[b][t][d] bf16 ; W1t[l][d] bf16 ; W2t[n=1536][k=1024] bf16 ; il bf16
// K1:    u = cos(xt @ rff_w + b)            (MFMA, bf16 out -> d_out scratch)
// LN:    z = layernorm(u)                   (bf16)
// K2:    gates = act([z_t||z_prev] @ W2t^T) (MFMA, fp32 out)
// K3:    c = f*c + i*g ; out[b][l][t] = sin(z)*c

typedef float f32x4 __attribute__((ext_vector_type(4)));
typedef short s16x8 __attribute__((ext_vector_type(8)));

__device__ __forceinline__ void gload_lds16(const void* g, void* l) {
  __builtin_amdgcn_global_load_lds(
      (const __attribute__((address_space(1))) void*)g,
      (__attribute__((address_space(3))) void*)l, 16, 0, 0);
}
__device__ __forceinline__ ushort f2bf(float f) {
  uint32_t u = __float_as_uint(f);
  return (ushort)((u + 0x7FFF + ((u >> 16) & 1)) >> 16);  // RNE
}
__device__ __forceinline__ float bf2f(ushort s) {
  return __uint_as_float(((uint32_t)s) << 16);
}

// ------------------------------------------------ prep: transpose fp32 -> bf16
// dst[c][r] = bf16(src[r][c]); grid (C/32, R/32, Z)
__global__ __launch_bounds__(256) void transpose_cvt(
    const float* __restrict__ src, long long srcZ, int src_ld,
    ushort* __restrict__ dst, long long dstZ, int dst_ld)
{
  __shared__ float tile[32][33];
  src += (size_t)blockIdx.z * srcZ;
  dst += (size_t)blockIdx.z * dstZ;
  const int c0 = blockIdx.x * 32, r0 = blockIdx.y * 32;
  const int tx = threadIdx.x & 31, ty = threadIdx.x >> 5;
#pragma unroll
  for (int i = 0; i < 4; ++i)
    tile[ty + i * 8][tx] = src[(size_t)(r0 + ty + i * 8) * src_ld + c0 + tx];
  __syncthreads();
#pragma unroll
  for (int i = 0; i < 4; ++i)
    dst[(size_t)(c0 + ty + i * 8) * dst_ld + r0 + tx] = f2bf(tile[tx][ty + i * 8]);
}

__global__ void cvt_bf16(const float* __restrict__ src, ushort* __restrict__ dst, int n) {
  const int i = blockIdx.x * 256 + threadIdx.x;
  if (i < n) dst[i] = f2bf(src[i]);
}

// ------------------------------------------------ K1: MFMA GEMM + cos epilogue
// A: xt bf16 [65536][512] row-major (k contig). Bt: W1t bf16 [512][512] (k contig).
// grid (N/128=4, M/128=512), 256 thr = 4 waves (2x2), wave tile 64x64.
__global__ __launch_bounds__(256) void k1_mfma(
    const ushort* __restrict__ A, const ushort* __restrict__ Bt,
    const float* __restrict__ bias, ushort* __restrict__ U)
{
  __shared__ __align__(16) short As[128 * 32];
  __shared__ __align__(16) short Bs[128 * 32];
  const int tid = threadIdx.x;
  const int lane = tid & 63, wid = tid >> 6;
  const int n0 = blockIdx.x * 128, r0 = blockIdx.y * 128;
  const int wr = wid >> 1, wc = wid & 1;
  const int fr = lane & 15, fq = lane >> 4;
  const int srow = wid * 32 + (lane >> 2);   // staging row (+p*16)
  const int scol = (lane & 3) * 8;           // staging k-chunk (8 bf16 = 16B)

  f32x4 acc[4][4];
#pragma unroll
  for (int m = 0; m < 4; ++m)
#pragma unroll
    for (int n = 0; n < 4; ++n)
#pragma unroll
      for (int j = 0; j < 4; ++j) acc[m][n][j] = 0.f;

  for (int k0 = 0; k0 < 512; k0 += 32) {
#pragma unroll
    for (int p = 0; p < 2; ++p) {
      gload_lds16(A  + (size_t)(r0 + srow + p * 16) * 512 + k0 + scol,
                  &As[(wid * 32 + p * 16) * 32]);
      gload_lds16(Bt + (size_t)(n0 + srow + p * 16) * 512 + k0 + scol,
                  &Bs[(wid * 32 + p * 16) * 32]);
    }
    __syncthreads();
    s16x8 a[4], b[4];
#pragma unroll
    for (int m = 0; m < 4; ++m)
      a[m] = *(const s16x8*)&As[(wr * 64 + m * 16 + fr) * 32 + fq * 8];
#pragma unroll
    for (int n = 0; n < 4; ++n)
      b[n] = *(const s16x8*)&Bs[(wc * 64 + n * 16 + fr) * 32 + fq * 8];
#pragma unroll
    for (int m = 0; m < 4; ++m)
#pragma unroll
      for (int n = 0; n < 4; ++n)
        acc[m][n] = __builtin_amdgcn_mfma_f32_16x16x32_bf16(a[m], b[n], acc[m][n], 0, 0, 0);
    __syncthreads();
  }

#pragma unroll
  for (int n = 0; n < 4; ++n) {
    const int col = n0 + wc * 64 + n * 16 + fr;
    const float bv = bias[col];
#pragma unroll
    for (int m = 0; m < 4; ++m) {
      const int rbase = r0 + wr * 64 + m * 16 + fq * 4;
#pragma unroll
      for (int j = 0; j < 4; ++j)
        U[(size_t)(rbase + j) * 512 + col] = f2bf(cosf(acc[m][n][j] + bv));
    }
  }
}

// ------------------------------------------------ LN: one wave per 512-row
__global__ __launch_bounds__(256) void ln_rows(
    const ushort* __restrict__ U, ushort* __restrict__ Z)
{
  const int row = blockIdx.x * 4 + (threadIdx.x >> 6);
  const int lane = threadIdx.x & 63;
  const size_t base = (size_t)row * 512 + lane * 8;
  const uint4 pk = *(const uint4*)(U + base);
  float v[8];
  v[0] = bf2f(pk.x & 0xffff); v[1] = bf2f(pk.x >> 16);
  v[2] = bf2f(pk.y & 0xffff); v[3] = bf2f(pk.y >> 16);
  v[4] = bf2f(pk.z & 0xffff); v[5] = bf2f(pk.z >> 16);
  v[6] = bf2f(pk.w & 0xffff); v[7] = bf2f(pk.w >> 16);
  float s = 0.f, s2 = 0.f;
#pragma unroll
  for (int j = 0; j < 8; ++j) { s += v[j]; s2 += v[j] * v[j]; }
#pragma unroll
  for (int m = 1; m < 64; m <<= 1) { s += __shfl_xor(s, m); s2 += __shfl_xor(s2, m); }
  const float mean = s * (1.f / 512.f);
  const float var = s2 * (1.f / 512.f) - mean * mean;
  const float inv = rsqrtf(var + 1e-5f);
  uint4 o;
  o.x = (uint)f2bf((v[0] - mean) * inv) | ((uint)f2bf((v[1] - mean) * inv) << 16);
  o.y = (uint)f2bf((v[2] - mean) * inv) | ((uint)f2bf((v[3] - mean) * inv) << 16);
  o.z = (uint)f2bf((v[4] - mean) * inv) | ((uint)f2bf((v[5] - mean) * inv) << 16);
  o.w = (uint)f2bf((v[6] - mean) * inv) | ((uint)f2bf((v[7] - mean) * inv) << 16);
  *(uint4*)(Z + base) = o;
}

// ------------------------------------------------ K2: gate GEMM (K=1024, N=1536)
// grid (12, B*Tc/128). A rows: k<512 -> z[row], k>=512 -> z[row-1] (t==0 -> il).
__global__ __launch_bounds__(256) void k2_mfma(
    const ushort* __restrict__ Z, const ushort* __restrict__ Wt,
    const ushort* __restrict__ IL,
    const float* __restrict__ b0, const float* __restrict__ b1,
    const float* __restrict__ b2,
    float* __restrict__ gates, int tc, int Tc)
{
  __shared__ __align__(16) short As[128 * 32];
  __shared__ __align__(16) short Bs[128 * 32];
  const int tid = threadIdx.x;
  const int lane = tid & 63, wid = tid >> 6;
  const int nb = Tc >> 7;
  const int b = blockIdx.y / nb, tb = blockIdx.y % nb;
  const int r0g = b * 1024 + tc + tb * 128;   // global z row base
  const int r0c = b * Tc + tb * 128;          // chunk-local gates row base
  const int n0 = blockIdx.x * 128;
  const int wr = wid >> 1, wc = wid & 1;
  const int fr = lane & 15, fq = lane >> 4;
  const int srow = wid * 32 + (lane >> 2);
  const int scol = (lane & 3) * 8;

  f32x4 acc[4][4];
#pragma unroll
  for (int m = 0; m < 4; ++m)
#pragma unroll
    for (int n = 0; n < 4; ++n)
#pragma unroll
      for (int j = 0; j < 4; ++j) acc[m][n][j] = 0.f;

  for (int k0 = 0; k0 < 1024; k0 += 32) {
#pragma unroll
    for (int p = 0; p < 2; ++p) {
      const int rr = r0g + srow + p * 16;
      const ushort* asrc;
      if (k0 < 512) {
        asrc = Z + (size_t)rr * 512 + k0 + scol;
      } else {
        const ushort* base = ((rr & 1023) == 0) ? IL : (Z + (size_t)(rr - 1) * 512);
        asrc = base + (k0 - 512) + scol;
      }
      gload_lds16(asrc, &As[(wid * 32 + p * 16) * 32]);
      gload_lds16(Wt + (size_t)(n0 + srow + p * 16) * 1024 + k0 + scol,
                  &Bs[(wid * 32 + p * 16) * 32]);
    }
    __syncthreads();
    s16x8 a[4], bfr[4];
#pragma unroll
    for (int m = 0; m < 4; ++m)
      a[m] = *(const s16x8*)&As[(wr * 64 + m * 16 + fr) * 32 + fq * 8];
#pragma unroll
    for (int n = 0; n < 4; ++n)
      bfr[n] = *(const s16x8*)&Bs[(wc * 64 + n * 16 + fr) * 32 + fq * 8];
#pragma unroll
    for (int m = 0; m < 4; ++m)
#pragma unroll
      for (int n = 0; n < 4; ++n)
        acc[m][n] = __builtin_amdgcn_mfma_f32_16x16x32_bf16(a[m], bfr[n], acc[m][n], 0, 0, 0);
    __syncthreads();
  }

  const int sel = n0 >> 9;  // block entirely within one gate (128 | 512)
  const float* bb = sel == 0 ? b0 : (sel == 1 ? b1 : b2);
#pragma unroll
  for (int n = 0; n < 4; ++n) {
    const int col = n0 + wc * 64 + n * 16 + fr;
    const float bv = bb[col & 511];
#pragma unroll
    for (int m = 0; m < 4; ++m) {
      const int rbase = wr * 64 + m * 16 + fq * 4;
#pragma unroll
      for (int j = 0; j < 4; ++j) {
        const float uu = acc[m][n][j] + bv;
        const float vv = (sel < 2) ? (1.f / (1.f + __expf(-uu)))
                                   : (2.f / (1.f + __expf(-2.f * uu)) - 1.f);
        gates[(size_t)(r0c + rbase + j) * 1536 + col] = vv;
      }
    }
  }
}

// ------------------------------------------------ K3: sequential scan
__global__ __launch_bounds__(128) void k3_scan(
    const float* __restrict__ gates, const ushort* __restrict__ z,
    const float* __restrict__ initc, float* __restrict__ out,
    float* __restrict__ cbuf, int tc, int Tc)
{
  __shared__ float tile[128][33];
  const int tid = threadIdx.x;
  const int b = blockIdx.y;
  const int l = blockIdx.x * 128 + tid;
  float c = (tc == 0) ? initc[l] : cbuf[b * 512 + l];
  const float* gb = gates + (size_t)b * Tc * 1536;
  const ushort* zb = z + ((size_t)b * 1024 + tc) * 512;

  for (int tt = 0; tt < Tc; tt += 32) {
#pragma unroll 8
    for (int j = 0; j < 32; ++j) {
      const int tau = tt + j;
      const float iv = gb[(size_t)tau * 1536 + l];
      const float fv = gb[(size_t)tau * 1536 + 512 + l];
      const float gv = gb[(size_t)tau * 1536 + 1024 + l];
      const float zv = bf2f(zb[(size_t)tau * 512 + l]);
      c = fmaf(fv, c, iv * gv);
      tile[tid][j] = sinf(zv) * c;
    }
    __syncthreads();
    const int col = tid & 31;
    const int rbase = tid >> 5;
    const size_t obase =
        ((size_t)b * 512 + blockIdx.x * 128) * 1024 + (size_t)(tc + tt) + col;
#pragma unroll
    for (int p = 0; p < 32; ++p) {
      const int row = rbase + p * 4;
      out[obase + (size_t)row * 1024] = tile[row][col];
    }
    __syncthreads();
  }
  cbuf[b * 512 + l] = c;
}

// ------------------------------------------------ launcher
extern "C" void kernel_launch(void* const* d_in, const int* in_sizes, int n_in,
                              void* d_out, int out_size, void* d_ws, size_t ws_size,
                              hipStream_t stream)
{
  const float* x  = (const float*)d_in[0];
  const float* W  = (const float*)d_in[1];
  const float* rb = (const float*)d_in[2];
  const float* wi = (const float*)d_in[3];
  const float* wf = (const float*)d_in[4];
  const float* wc = (const float*)d_in[5];
  const float* ri = (const float*)d_in[6];
  const float* rf = (const float*)d_in[7];
  const float* rc = (const float*)d_in[8];
  const float* bi = (const float*)d_in[9];
  const float* bfo = (const float*)d_in[10];
  const float* bc = (const float*)d_in[11];
  const float* il = (const float*)d_in[12];
  const float* ic = (const float*)d_in[13];
  float* out = (float*)d_out;

  char* ws = (char*)d_ws;
  size_t off = 0;
  auto alloc = [&](size_t bytes) -> void* {
    void* p = ws + off;
    off = (off + bytes + 255) & ~(size_t)255;
    return p;
  };
  ushort* z    = (ushort*)alloc((size_t)65536 * 512 * 2);   // 67.1 MB
  ushort* W1t  = (ushort*)alloc((size_t)512 * 512 * 2);
  ushort* W2t  = (ushort*)alloc((size_t)1536 * 1024 * 2);
  ushort* ilb  = (ushort*)alloc(512 * 2);
  float*  cbuf = (float*)alloc((size_t)64 * 512 * 4);
  const size_t fixed_end = off;
  ushort* xt   = (ushort*)alloc((size_t)65536 * 512 * 2);   // dead after K1
  float* gates = (float*)(ws + fixed_end);                  // aliases xt region
  ushort* u    = (ushort*)d_out;                            // dead before K3

  int Tc = 1024;
  while (Tc > 128 && fixed_end + (size_t)64 * Tc * 1536 * 4 > ws_size) Tc >>= 1;

  // prep: weights
  transpose_cvt<<<dim3(16, 16, 1), 256, 0, stream>>>(W, 0, 512, W1t, 0, 512);
  const float* gw[6] = {wi, ri, wf, rf, wc, rc};
  for (int s = 0; s < 3; ++s) {
    transpose_cvt<<<dim3(16, 16, 1), 256, 0, stream>>>(
        gw[s * 2 + 0], 0, 512, W2t + (size_t)s * 512 * 1024, 0, 1024);
    transpose_cvt<<<dim3(16, 16, 1), 256, 0, stream>>>(
        gw[s * 2 + 1], 0, 512, W2t + (size_t)s * 512 * 1024 + 512, 0, 1024);
  }
  cvt_bf16<<<2, 256, 0, stream>>>(il, ilb, 512);
  // prep: xt[b][t][d] = x[b][d][t]
  transpose_cvt<<<dim3(32, 16, 64), 256, 0, stream>>>(
      x, (long long)512 * 1024, 1024, xt, (long long)1024 * 512, 512);

  k1_mfma<<<dim3(4, 512), 256, 0, stream>>>(xt, W1t, rb, u);
  ln_rows<<<16384, 256, 0, stream>>>(u, z);

  for (int tc = 0; tc < 1024; tc += Tc) {
    k2_mfma<<<dim3(12, 64 * (Tc >> 7)), 256, 0, stream>>>(
        z, W2t, ilb, bi, bfo, bc, gates, tc, Tc);
    k3_scan<<<dim3(4, 64), 128, 0, stream>>>(gates, z, ic, out, cbuf, tc, Tc);
  }
}

// Round 3
// 1133.083 us; speedup vs baseline: 19.6806x; 1.1952x over previous
//
#include <hip/hip_runtime.h>
#include <hip/hip_bf16.h>
#include <cstdint>
#include <cstddef>

// B=64, D=512, T=1024, L=512
// prep:  xt[b][t][d] bf16 ; W1t[l][d] bf16 ; W2t[n=1536][k=1024] bf16 ; il bf16
// K1:    u = cos(xt @ rff_w + b)            (MFMA, bf16 out -> d_out scratch)
// LN:    z = layernorm(u)                   (bf16)
// K2:    gates = act([z_t||z_prev] @ W2t^T) (MFMA, fp32 out)
// scan (segmented, 3 phases):
//   k3a: per 64-step segment: A = prod f, Bc = local scan from 0
//   k3b: sequential combine over segments -> cstart per segment
//   k3c: re-run segment from cstart, h = sin(z)*c, LDS transpose -> out[b][l][t]

typedef float f32x4 __attribute__((ext_vector_type(4)));
typedef short s16x8 __attribute__((ext_vector_type(8)));

__device__ __forceinline__ void gload_lds16(const void* g, void* l) {
  __builtin_amdgcn_global_load_lds(
      (const __attribute__((address_space(1))) void*)g,
      (__attribute__((address_space(3))) void*)l, 16, 0, 0);
}
__device__ __forceinline__ ushort f2bf(float f) {
  uint32_t u = __float_as_uint(f);
  return (ushort)((u + 0x7FFF + ((u >> 16) & 1)) >> 16);  // RNE
}
__device__ __forceinline__ float bf2f(ushort s) {
  return __uint_as_float(((uint32_t)s) << 16);
}

// ------------------------------------------------ prep: transpose fp32 -> bf16
__global__ __launch_bounds__(256) void transpose_cvt(
    const float* __restrict__ src, long long srcZ, int src_ld,
    ushort* __restrict__ dst, long long dstZ, int dst_ld)
{
  __shared__ float tile[32][33];
  src += (size_t)blockIdx.z * srcZ;
  dst += (size_t)blockIdx.z * dstZ;
  const int c0 = blockIdx.x * 32, r0 = blockIdx.y * 32;
  const int tx = threadIdx.x & 31, ty = threadIdx.x >> 5;
#pragma unroll
  for (int i = 0; i < 4; ++i)
    tile[ty + i * 8][tx] = src[(size_t)(r0 + ty + i * 8) * src_ld + c0 + tx];
  __syncthreads();
#pragma unroll
  for (int i = 0; i < 4; ++i)
    dst[(size_t)(c0 + ty + i * 8) * dst_ld + r0 + tx] = f2bf(tile[tx][ty + i * 8]);
}

__global__ void cvt_bf16(const float* __restrict__ src, ushort* __restrict__ dst, int n) {
  const int i = blockIdx.x * 256 + threadIdx.x;
  if (i < n) dst[i] = f2bf(src[i]);
}

// ------------------------------------------------ K1: MFMA GEMM + cos epilogue
__global__ __launch_bounds__(256) void k1_mfma(
    const ushort* __restrict__ A, const ushort* __restrict__ Bt,
    const float* __restrict__ bias, ushort* __restrict__ U)
{
  __shared__ __align__(16) short As[128 * 32];
  __shared__ __align__(16) short Bs[128 * 32];
  const int tid = threadIdx.x;
  const int lane = tid & 63, wid = tid >> 6;
  const int n0 = blockIdx.x * 128, r0 = blockIdx.y * 128;
  const int wr = wid >> 1, wc = wid & 1;
  const int fr = lane & 15, fq = lane >> 4;
  const int srow = wid * 32 + (lane >> 2);
  const int scol = (lane & 3) * 8;

  f32x4 acc[4][4];
#pragma unroll
  for (int m = 0; m < 4; ++m)
#pragma unroll
    for (int n = 0; n < 4; ++n)
#pragma unroll
      for (int j = 0; j < 4; ++j) acc[m][n][j] = 0.f;

  for (int k0 = 0; k0 < 512; k0 += 32) {
#pragma unroll
    for (int p = 0; p < 2; ++p) {
      gload_lds16(A  + (size_t)(r0 + srow + p * 16) * 512 + k0 + scol,
                  &As[(wid * 32 + p * 16) * 32]);
      gload_lds16(Bt + (size_t)(n0 + srow + p * 16) * 512 + k0 + scol,
                  &Bs[(wid * 32 + p * 16) * 32]);
    }
    __syncthreads();
    s16x8 a[4], b[4];
#pragma unroll
    for (int m = 0; m < 4; ++m)
      a[m] = *(const s16x8*)&As[(wr * 64 + m * 16 + fr) * 32 + fq * 8];
#pragma unroll
    for (int n = 0; n < 4; ++n)
      b[n] = *(const s16x8*)&Bs[(wc * 64 + n * 16 + fr) * 32 + fq * 8];
#pragma unroll
    for (int m = 0; m < 4; ++m)
#pragma unroll
      for (int n = 0; n < 4; ++n)
        acc[m][n] = __builtin_amdgcn_mfma_f32_16x16x32_bf16(a[m], b[n], acc[m][n], 0, 0, 0);
    __syncthreads();
  }

#pragma unroll
  for (int n = 0; n < 4; ++n) {
    const int col = n0 + wc * 64 + n * 16 + fr;
    const float bv = bias[col];
#pragma unroll
    for (int m = 0; m < 4; ++m) {
      const int rbase = r0 + wr * 64 + m * 16 + fq * 4;
#pragma unroll
      for (int j = 0; j < 4; ++j)
        U[(size_t)(rbase + j) * 512 + col] = f2bf(cosf(acc[m][n][j] + bv));
    }
  }
}

// ------------------------------------------------ LN: one wave per 512-row
__global__ __launch_bounds__(256) void ln_rows(
    const ushort* __restrict__ U, ushort* __restrict__ Z)
{
  const int row = blockIdx.x * 4 + (threadIdx.x >> 6);
  const int lane = threadIdx.x & 63;
  const size_t base = (size_t)row * 512 + lane * 8;
  const uint4 pk = *(const uint4*)(U + base);
  float v[8];
  v[0] = bf2f(pk.x & 0xffff); v[1] = bf2f(pk.x >> 16);
  v[2] = bf2f(pk.y & 0xffff); v[3] = bf2f(pk.y >> 16);
  v[4] = bf2f(pk.z & 0xffff); v[5] = bf2f(pk.z >> 16);
  v[6] = bf2f(pk.w & 0xffff); v[7] = bf2f(pk.w >> 16);
  float s = 0.f, s2 = 0.f;
#pragma unroll
  for (int j = 0; j < 8; ++j) { s += v[j]; s2 += v[j] * v[j]; }
#pragma unroll
  for (int m = 1; m < 64; m <<= 1) { s += __shfl_xor(s, m); s2 += __shfl_xor(s2, m); }
  const float mean = s * (1.f / 512.f);
  const float var = s2 * (1.f / 512.f) - mean * mean;
  const float inv = rsqrtf(var + 1e-5f);
  uint4 o;
  o.x = (uint)f2bf((v[0] - mean) * inv) | ((uint)f2bf((v[1] - mean) * inv) << 16);
  o.y = (uint)f2bf((v[2] - mean) * inv) | ((uint)f2bf((v[3] - mean) * inv) << 16);
  o.z = (uint)f2bf((v[4] - mean) * inv) | ((uint)f2bf((v[5] - mean) * inv) << 16);
  o.w = (uint)f2bf((v[6] - mean) * inv) | ((uint)f2bf((v[7] - mean) * inv) << 16);
  *(uint4*)(Z + base) = o;
}

// ------------------------------------------------ K2: gate GEMM (K=1024, N=1536)
__global__ __launch_bounds__(256) void k2_mfma(
    const ushort* __restrict__ Z, const ushort* __restrict__ Wt,
    const ushort* __restrict__ IL,
    const float* __restrict__ b0, const float* __restrict__ b1,
    const float* __restrict__ b2,
    float* __restrict__ gates, int tc, int Tc)
{
  __shared__ __align__(16) short As[128 * 32];
  __shared__ __align__(16) short Bs[128 * 32];
  const int tid = threadIdx.x;
  const int lane = tid & 63, wid = tid >> 6;
  const int nb = Tc >> 7;
  const int b = blockIdx.y / nb, tb = blockIdx.y % nb;
  const int r0g = b * 1024 + tc + tb * 128;
  const int r0c = b * Tc + tb * 128;
  const int n0 = blockIdx.x * 128;
  const int wr = wid >> 1, wc = wid & 1;
  const int fr = lane & 15, fq = lane >> 4;
  const int srow = wid * 32 + (lane >> 2);
  const int scol = (lane & 3) * 8;

  f32x4 acc[4][4];
#pragma unroll
  for (int m = 0; m < 4; ++m)
#pragma unroll
    for (int n = 0; n < 4; ++n)
#pragma unroll
      for (int j = 0; j < 4; ++j) acc[m][n][j] = 0.f;

  for (int k0 = 0; k0 < 1024; k0 += 32) {
#pragma unroll
    for (int p = 0; p < 2; ++p) {
      const int rr = r0g + srow + p * 16;
      const ushort* asrc;
      if (k0 < 512) {
        asrc = Z + (size_t)rr * 512 + k0 + scol;
      } else {
        const ushort* base = ((rr & 1023) == 0) ? IL : (Z + (size_t)(rr - 1) * 512);
        asrc = base + (k0 - 512) + scol;
      }
      gload_lds16(asrc, &As[(wid * 32 + p * 16) * 32]);
      gload_lds16(Wt + (size_t)(n0 + srow + p * 16) * 1024 + k0 + scol,
                  &Bs[(wid * 32 + p * 16) * 32]);
    }
    __syncthreads();
    s16x8 a[4], bfr[4];
#pragma unroll
    for (int m = 0; m < 4; ++m)
      a[m] = *(const s16x8*)&As[(wr * 64 + m * 16 + fr) * 32 + fq * 8];
#pragma unroll
    for (int n = 0; n < 4; ++n)
      bfr[n] = *(const s16x8*)&Bs[(wc * 64 + n * 16 + fr) * 32 + fq * 8];
#pragma unroll
    for (int m = 0; m < 4; ++m)
#pragma unroll
      for (int n = 0; n < 4; ++n)
        acc[m][n] = __builtin_amdgcn_mfma_f32_16x16x32_bf16(a[m], bfr[n], acc[m][n], 0, 0, 0);
    __syncthreads();
  }

  const int sel = n0 >> 9;
  const float* bb = sel == 0 ? b0 : (sel == 1 ? b1 : b2);
#pragma unroll
  for (int n = 0; n < 4; ++n) {
    const int col = n0 + wc * 64 + n * 16 + fr;
    const float bv = bb[col & 511];
#pragma unroll
    for (int m = 0; m < 4; ++m) {
      const int rbase = wr * 64 + m * 16 + fq * 4;
#pragma unroll
      for (int j = 0; j < 4; ++j) {
        const float uu = acc[m][n][j] + bv;
        const float vv = (sel < 2) ? (1.f / (1.f + __expf(-uu)))
                                   : (2.f / (1.f + __expf(-2.f * uu)) - 1.f);
        gates[(size_t)(r0c + rbase + j) * 1536 + col] = vv;
      }
    }
  }
}

// ------------------------------------------------ scan phase A: segment summaries
// grid (2, B, SEGc), 256 thr. A = prod f over 64 steps, Bc = scan from c=0.
__global__ __launch_bounds__(256) void k3a_seg(
    const float* __restrict__ gates, float* __restrict__ Aseg,
    float* __restrict__ Bseg, int Tc)
{
  const int l = blockIdx.x * 256 + threadIdx.x;
  const int b = blockIdx.y, s = blockIdx.z;
  const int SEGc = Tc >> 6;
  const float* gb = gates + ((size_t)(b * Tc + s * 64)) * 1536 + l;
  float A = 1.f, c = 0.f;
#pragma unroll 8
  for (int j = 0; j < 64; ++j) {
    const float iv = gb[(size_t)j * 1536];
    const float fv = gb[(size_t)j * 1536 + 512];
    const float gv = gb[(size_t)j * 1536 + 1024];
    A *= fv;
    c = fmaf(fv, c, iv * gv);
  }
  const size_t o = (size_t)(b * SEGc + s) * 512 + l;
  Aseg[o] = A;
  Bseg[o] = c;
}

// ------------------------------------------------ scan phase B: combine segments
// grid (B), 512 thr. Sequential over SEGc segments; carries c across chunks.
__global__ __launch_bounds__(512) void k3b_comb(
    const float* __restrict__ Aseg, const float* __restrict__ Bseg,
    const float* __restrict__ initc, float* __restrict__ cstart,
    float* __restrict__ cbuf, int tc, int Tc)
{
  const int b = blockIdx.x, l = threadIdx.x;
  const int SEGc = Tc >> 6;
  float c = (tc == 0) ? initc[l] : cbuf[b * 512 + l];
  for (int s = 0; s < SEGc; ++s) {
    const size_t o = (size_t)(b * SEGc + s) * 512 + l;
    cstart[o] = c;
    c = fmaf(Aseg[o], c, Bseg[o]);
  }
  cbuf[b * 512 + l] = c;
}

// ------------------------------------------------ scan phase C: emit outputs
// grid (4, B, SEGc), 128 thr. h = sin(z)*c ; LDS transpose ; coalesced store.
__global__ __launch_bounds__(128) void k3c_emit(
    const float* __restrict__ gates, const ushort* __restrict__ Z,
    const float* __restrict__ cstart, float* __restrict__ out,
    int tc, int Tc)
{
  __shared__ float tile[128][65];
  const int tid = threadIdx.x;
  const int l0 = blockIdx.x * 128;
  const int b = blockIdx.y, s = blockIdx.z;
  const int SEGc = Tc >> 6;
  const int l = l0 + tid;

  float c = cstart[(size_t)(b * SEGc + s) * 512 + l];
  const float* gb = gates + ((size_t)(b * Tc + s * 64)) * 1536 + l;
  const ushort* zb = Z + ((size_t)(b * 1024 + tc + s * 64)) * 512 + l;
#pragma unroll 8
  for (int j = 0; j < 64; ++j) {
    const float iv = gb[(size_t)j * 1536];
    const float fv = gb[(size_t)j * 1536 + 512];
    const float gv = gb[(size_t)j * 1536 + 1024];
    const float zv = bf2f(zb[(size_t)j * 512]);
    c = fmaf(fv, c, iv * gv);
    tile[tid][j] = sinf(zv) * c;
  }
  __syncthreads();
  const int col = tid & 63, rhalf = tid >> 6;  // 2 waves: rows rhalf+2p
  const size_t obase = ((size_t)b * 512 + l0) * 1024 + (size_t)(tc + s * 64) + col;
#pragma unroll
  for (int p = 0; p < 64; ++p) {
    const int row = rhalf + p * 2;
    out[obase + (size_t)row * 1024] = tile[row][col];
  }
}

// ------------------------------------------------ launcher
extern "C" void kernel_launch(void* const* d_in, const int* in_sizes, int n_in,
                              void* d_out, int out_size, void* d_ws, size_t ws_size,
                              hipStream_t stream)
{
  const float* x  = (const float*)d_in[0];
  const float* W  = (const float*)d_in[1];
  const float* rb = (const float*)d_in[2];
  const float* wi = (const float*)d_in[3];
  const float* wf = (const float*)d_in[4];
  const float* wc = (const float*)d_in[5];
  const float* ri = (const float*)d_in[6];
  const float* rf = (const float*)d_in[7];
  const float* rc = (const float*)d_in[8];
  const float* bi = (const float*)d_in[9];
  const float* bfo = (const float*)d_in[10];
  const float* bc = (const float*)d_in[11];
  const float* il = (const float*)d_in[12];
  const float* ic = (const float*)d_in[13];
  float* out = (float*)d_out;

  char* ws = (char*)d_ws;
  size_t off = 0;
  auto alloc = [&](size_t bytes) -> void* {
    void* p = ws + off;
    off = (off + bytes + 255) & ~(size_t)255;
    return p;
  };
  ushort* z    = (ushort*)alloc((size_t)65536 * 512 * 2);   // 67.1 MB
  ushort* W1t  = (ushort*)alloc((size_t)512 * 512 * 2);
  ushort* W2t  = (ushort*)alloc((size_t)1536 * 1024 * 2);
  ushort* ilb  = (ushort*)alloc(512 * 2);
  float*  cbuf = (float*)alloc((size_t)64 * 512 * 4);
  float*  Aseg = (float*)alloc((size_t)64 * 16 * 512 * 4);  // 2 MB
  float*  Bseg = (float*)alloc((size_t)64 * 16 * 512 * 4);
  float*  cstart = (float*)alloc((size_t)64 * 16 * 512 * 4);
  const size_t fixed_end = off;
  ushort* xt   = (ushort*)alloc((size_t)65536 * 512 * 2);   // dead after K1
  float* gates = (float*)(ws + fixed_end);                  // aliases xt region
  ushort* u    = (ushort*)d_out;                            // dead before k3c

  int Tc = 1024;
  while (Tc > 128 && fixed_end + (size_t)64 * Tc * 1536 * 4 > ws_size) Tc >>= 1;

  // prep: weights
  transpose_cvt<<<dim3(16, 16, 1), 256, 0, stream>>>(W, 0, 512, W1t, 0, 512);
  const float* gw[6] = {wi, ri, wf, rf, wc, rc};
  for (int s = 0; s < 3; ++s) {
    transpose_cvt<<<dim3(16, 16, 1), 256, 0, stream>>>(
        gw[s * 2 + 0], 0, 512, W2t + (size_t)s * 512 * 1024, 0, 1024);
    transpose_cvt<<<dim3(16, 16, 1), 256, 0, stream>>>(
        gw[s * 2 + 1], 0, 512, W2t + (size_t)s * 512 * 1024 + 512, 0, 1024);
  }
  cvt_bf16<<<2, 256, 0, stream>>>(il, ilb, 512);
  transpose_cvt<<<dim3(32, 16, 64), 256, 0, stream>>>(
      x, (long long)512 * 1024, 1024, xt, (long long)1024 * 512, 512);

  k1_mfma<<<dim3(4, 512), 256, 0, stream>>>(xt, W1t, rb, u);
  ln_rows<<<16384, 256, 0, stream>>>(u, z);

  for (int tc = 0; tc < 1024; tc += Tc) {
    const int SEGc = Tc >> 6;
    k2_mfma<<<dim3(12, 64 * (Tc >> 7)), 256, 0, stream>>>(
        z, W2t, ilb, bi, bfo, bc, gates, tc, Tc);
    k3a_seg<<<dim3(2, 64, SEGc), 256, 0, stream>>>(gates, Aseg, Bseg, Tc);
    k3b_comb<<<64, 512, 0, stream>>>(Aseg, Bseg, ic, cstart, cbuf, tc, Tc);
    k3c_emit<<<dim3(4, 64, SEGc), 128, 0, stream>>>(gates, z, cstart, out, tc, Tc);
  }
}